// Round 2
// baseline (1210.886 us; speedup 1.0000x reference)
//
#include <hip/hip_runtime.h>
#include <stdint.h>
#include <stddef.h>

typedef unsigned short u16t;
typedef unsigned int   u32t;
typedef __bf16  bf16x8 __attribute__((ext_vector_type(8)));
typedef float   f32x4  __attribute__((ext_vector_type(4)));

#define NN 50000
#define NE 800000
#define NG 16
#define DD 64
#define HH 128

#define AS 264   // A-tile LDS row stride (256 + 8 bf16 pad) -> 2-way bank alias (free)
#define HS 136   // h-tile LDS row stride (128 + 8)
#define NAS 200  // node A-tile stride (192 + 8)

static __device__ __forceinline__ float bf2f(u16t h){
  return __uint_as_float(((u32t)h) << 16);
}
static __device__ __forceinline__ u16t f2bf(float f){
  u32t u = __float_as_uint(f);
  u32t r = u + 0x7FFFu + ((u >> 16) & 1u);   // RNE
  return (u16t)(r >> 16);
}
static __device__ __forceinline__ bf16x8 ldfrag(const u16t* p){
  return __builtin_bit_cast(bf16x8, *(const uint4*)p);
}

// load 16 consecutive logical elements (fp32 or bf16 array) -> 16 bf16 into LDS
static __device__ __forceinline__ void stage16(u16t* dst, const void* src, size_t eoff, bool f32){
  if (!f32){
    const u16t* p = (const u16t*)src + eoff;
    *(uint4*)(dst)     = *(const uint4*)(p);
    *(uint4*)(dst + 8) = *(const uint4*)(p + 8);
  } else {
    const float* p = (const float*)src + eoff;
    #pragma unroll
    for (int j = 0; j < 16; j += 4){
      float4 v = *(const float4*)(p + j);
      dst[j+0] = f2bf(v.x); dst[j+1] = f2bf(v.y);
      dst[j+2] = f2bf(v.z); dst[j+3] = f2bf(v.w);
    }
  }
}
static __device__ __forceinline__ float ldb(const void* b, int i, bool f32){
  return f32 ? ((const float*)b)[i] : bf2f(((const u16t*)b)[i]);
}
static __device__ __forceinline__ void store1(void* out, size_t idx, float v, bool f32){
  if (f32) ((float*)out)[idx] = v;
  else     ((u16t*)out)[idx]  = f2bf(v);
}

// Decide fp32 vs bf16 by interpreting x's first 256 u16 as bf16:
// true-bf16 N(0,1) data -> ~0 implausible; fp32 data -> ~45% implausible (low mantissa halves).
__global__ void detect_kernel(const void* x, int* flag){
  if (threadIdx.x == 0 && blockIdx.x == 0){
    const u16t* xh = (const u16t*)x;
    int bad = 0;
    for (int i = 0; i < 256; ++i){
      float a = fabsf(bf2f(xh[i]));
      if (!(a > 1e-6f && a < 1e4f)) bad++;   // NaN also lands here
    }
    *flag = (bad > 32) ? 1 : 0;   // 1 = inputs are fp32
  }
}

// Repack W[K][Ncols] (row-major, fp32 or bf16) into MFMA-B-fragment order (bf16):
// Wp[((kk*Ncols + n)*32) + t] = W[kk*32 + t][n], t = quad*8 + j contiguous.
__global__ void repack_kernel(const void* __restrict__ W, u16t* __restrict__ Wp,
                              int K, int Ncols, const int* __restrict__ flag){
  const bool f32 = (*flag != 0);
  int idx = blockIdx.x * 256 + threadIdx.x;
  if (idx >= K * Ncols) return;
  int per = Ncols * 32;
  int kk  = idx / per;
  int rem = idx - kk * per;
  int n   = rem >> 5;
  int t   = rem & 31;
  int src = (kk * 32 + t) * Ncols + n;
  float v = f32 ? ((const float*)W)[src] : bf2f(((const u16t*)W)[src]);
  Wp[idx] = f2bf(v);
}

__global__ __launch_bounds__(256) void edge_kernel(
  const void* __restrict__ x, const int* __restrict__ ei, const void* __restrict__ e,
  const void* __restrict__ u, const int* __restrict__ batch,
  const u16t* __restrict__ Wp1, const void* __restrict__ b1,
  const u16t* __restrict__ Wp2, const void* __restrict__ b2,
  const u16t* __restrict__ WpA1, const void* __restrict__ ba1,
  const u16t* __restrict__ WpA2, const void* __restrict__ ba2,
  void* __restrict__ d_out, float* __restrict__ agg, float* __restrict__ edge_agg,
  const int* __restrict__ flag, int ntiles)
{
  __shared__ u16t  sA[64 * AS];
  __shared__ u16t  sH[64 * HS];
  __shared__ float sEagg[NG * DD];
  __shared__ int   sDst[64];
  __shared__ int   sG[64];

  const bool f32 = (*flag != 0);
  const size_t OUT_E = (size_t)NN * DD;   // element offset of e_new section in d_out

  const int tid  = threadIdx.x;
  const int wave = tid >> 6;
  const int lane = tid & 63;
  const int l15  = lane & 15;
  const int quad = lane >> 4;
  const int el   = tid >> 2;   // local edge 0..63 (4 threads/edge)
  const int q    = tid & 3;    // 16-col chunk within D=64

  for (int i = tid; i < NG * DD; i += 256) sEagg[i] = 0.f;

  const f32x4 vzero = {0.f, 0.f, 0.f, 0.f};

  for (int tile = blockIdx.x; tile < ntiles; tile += gridDim.x){
    const int base = tile * 64;

    // ---- stage input tile [xs | xd | e | u_src], bf16, 64 x 256 ----
    {
      const int eidx = base + el;
      const int s = ei[eidx];
      const int d = ei[NE + eidx];
      const int g = batch[s];
      if (q == 0) sDst[el] = d;
      if (q == 1) sG[el]   = g;
      u16t* row = sA + el * AS + q * 16;
      stage16(row +   0, x, (size_t)s    * DD + q * 16, f32);
      stage16(row +  64, x, (size_t)d    * DD + q * 16, f32);
      stage16(row + 128, e, (size_t)eidx * DD + q * 16, f32);
      stage16(row + 192, u, (size_t)g    * DD + q * 16, f32);
    }
    __syncthreads();

    const int colbase = wave * 32;  // layer-1 col range per wave
    const int n0      = wave * 16;  // layer-2 col range per wave

    // ---- edge MLP layer 1: [64x256] @ [256x128] ----
    f32x4 acc[4][2];
    #pragma unroll
    for (int rt = 0; rt < 4; ++rt){ acc[rt][0] = vzero; acc[rt][1] = vzero; }
    for (int kk = 0; kk < 8; ++kk){
      bf16x8 af[4], bw[2];
      #pragma unroll
      for (int rt = 0; rt < 4; ++rt)
        af[rt] = ldfrag(&sA[(rt * 16 + l15) * AS + kk * 32 + quad * 8]);
      #pragma unroll
      for (int ct = 0; ct < 2; ++ct)
        bw[ct] = ldfrag(&Wp1[((kk * HH + colbase + ct * 16 + l15) << 5) + quad * 8]);
      #pragma unroll
      for (int rt = 0; rt < 4; ++rt)
        #pragma unroll
        for (int ct = 0; ct < 2; ++ct)
          acc[rt][ct] = __builtin_amdgcn_mfma_f32_16x16x32_bf16(af[rt], bw[ct], acc[rt][ct], 0, 0, 0);
    }
    #pragma unroll
    for (int ct = 0; ct < 2; ++ct){
      const int col = colbase + ct * 16 + l15;
      const float bias = ldb(b1, col, f32);
      #pragma unroll
      for (int rt = 0; rt < 4; ++rt)
        #pragma unroll
        for (int r = 0; r < 4; ++r){
          float h = fmaxf(acc[rt][ct][r] + bias, 0.f);
          sH[(rt * 16 + quad * 4 + r) * HS + col] = f2bf(h);
        }
    }
    __syncthreads();

    // ---- edge MLP layer 2: [64x128] @ [128x64] -> e_new ----
    f32x4 acc2[4];
    #pragma unroll
    for (int rt = 0; rt < 4; ++rt) acc2[rt] = vzero;
    for (int kk = 0; kk < 4; ++kk){
      bf16x8 af[4];
      #pragma unroll
      for (int rt = 0; rt < 4; ++rt)
        af[rt] = ldfrag(&sH[(rt * 16 + l15) * HS + kk * 32 + quad * 8]);
      bf16x8 bw = ldfrag(&Wp2[((kk * 64 + n0 + l15) << 5) + quad * 8]);
      #pragma unroll
      for (int rt = 0; rt < 4; ++rt)
        acc2[rt] = __builtin_amdgcn_mfma_f32_16x16x32_bf16(af[rt], bw, acc2[rt], 0, 0, 0);
    }
    float enew[4][4];
    {
      const int col = n0 + l15;
      const float bias = ldb(b2, col, f32);
      #pragma unroll
      for (int rt = 0; rt < 4; ++rt)
        #pragma unroll
        for (int r = 0; r < 4; ++r){
          float v = acc2[rt][r] + bias;
          enew[rt][r] = v;
          const int row = rt * 16 + quad * 4 + r;
          store1(d_out, OUT_E + (size_t)(base + row) * DD + col, v, f32);
          sA[row * AS + 128 + col] = f2bf(v);   // e-slot <- e_new for attention input
          atomicAdd(&sEagg[sG[row] * DD + col], v);
        }
    }
    __syncthreads();

    // ---- attention MLP layer 1 ----
    f32x4 acc3[4][2];
    #pragma unroll
    for (int rt = 0; rt < 4; ++rt){ acc3[rt][0] = vzero; acc3[rt][1] = vzero; }
    for (int kk = 0; kk < 8; ++kk){
      bf16x8 af[4], bw[2];
      #pragma unroll
      for (int rt = 0; rt < 4; ++rt)
        af[rt] = ldfrag(&sA[(rt * 16 + l15) * AS + kk * 32 + quad * 8]);
      #pragma unroll
      for (int ct = 0; ct < 2; ++ct)
        bw[ct] = ldfrag(&WpA1[((kk * HH + colbase + ct * 16 + l15) << 5) + quad * 8]);
      #pragma unroll
      for (int rt = 0; rt < 4; ++rt)
        #pragma unroll
        for (int ct = 0; ct < 2; ++ct)
          acc3[rt][ct] = __builtin_amdgcn_mfma_f32_16x16x32_bf16(af[rt], bw[ct], acc3[rt][ct], 0, 0, 0);
    }
    #pragma unroll
    for (int ct = 0; ct < 2; ++ct){
      const int col = colbase + ct * 16 + l15;
      const float bias = ldb(ba1, col, f32);
      #pragma unroll
      for (int rt = 0; rt < 4; ++rt)
        #pragma unroll
        for (int r = 0; r < 4; ++r){
          float h = fmaxf(acc3[rt][ct][r] + bias, 0.f);
          sH[(rt * 16 + quad * 4 + r) * HS + col] = f2bf(h);
        }
    }
    __syncthreads();

    // ---- attention MLP layer 2 -> sigmoid -> scatter e_new*a into agg[dst] ----
    f32x4 acc4[4];
    #pragma unroll
    for (int rt = 0; rt < 4; ++rt) acc4[rt] = vzero;
    for (int kk = 0; kk < 4; ++kk){
      bf16x8 af[4];
      #pragma unroll
      for (int rt = 0; rt < 4; ++rt)
        af[rt] = ldfrag(&sH[(rt * 16 + l15) * HS + kk * 32 + quad * 8]);
      bf16x8 bw = ldfrag(&WpA2[((kk * 64 + n0 + l15) << 5) + quad * 8]);
      #pragma unroll
      for (int rt = 0; rt < 4; ++rt)
        acc4[rt] = __builtin_amdgcn_mfma_f32_16x16x32_bf16(af[rt], bw, acc4[rt], 0, 0, 0);
    }
    {
      const int col = n0 + l15;
      const float bias = ldb(ba2, col, f32);
      #pragma unroll
      for (int rt = 0; rt < 4; ++rt)
        #pragma unroll
        for (int r = 0; r < 4; ++r){
          float sv = acc4[rt][r] + bias;
          float av = 1.0f / (1.0f + __expf(-sv));
          const int row = rt * 16 + quad * 4 + r;
          atomicAdd(&agg[(size_t)sDst[row] * DD + col], enew[rt][r] * av);
        }
    }
    __syncthreads();   // protect sA/sDst/sG before next tile's staging
  }

  // flush per-block edge_agg partial
  for (int i = tid; i < NG * DD; i += 256)
    atomicAdd(&edge_agg[i], sEagg[i]);
}

__global__ __launch_bounds__(256) void node_kernel(
  const void* __restrict__ x, const float* __restrict__ agg, const void* __restrict__ u,
  const int* __restrict__ batch,
  const u16t* __restrict__ WpN1, const void* __restrict__ bn1,
  const u16t* __restrict__ WpN2, const void* __restrict__ bn2,
  void* __restrict__ d_out, float* __restrict__ node_agg, const int* __restrict__ flag)
{
  __shared__ u16t  sA[64 * NAS];
  __shared__ u16t  sH[64 * HS];
  __shared__ float sNagg[NG * DD];
  __shared__ int   sGn[64];

  const bool f32 = (*flag != 0);

  const int tid  = threadIdx.x;
  const int wave = tid >> 6;
  const int lane = tid & 63;
  const int l15  = lane & 15;
  const int quad = lane >> 4;
  const int base = blockIdx.x * 64;

  for (int i = tid; i < NG * DD; i += 256) sNagg[i] = 0.f;

  // ---- stage [x | agg | u_batch], 64 x 192 bf16 ----
  {
    const int el = tid >> 2;
    const int q  = tid & 3;
    int n  = base + el;
    int nc = n < NN ? n : (NN - 1);
    int g  = batch[nc];
    if (q == 0) sGn[el] = g;
    u16t* row = sA + el * NAS + q * 16;
    stage16(row + 0, x, (size_t)nc * DD + q * 16, f32);
    const float* pa = agg + (size_t)nc * DD + q * 16;
    #pragma unroll
    for (int j = 0; j < 16; j += 4){
      float4 v = *(const float4*)(pa + j);
      row[64 + j + 0] = f2bf(v.x);
      row[64 + j + 1] = f2bf(v.y);
      row[64 + j + 2] = f2bf(v.z);
      row[64 + j + 3] = f2bf(v.w);
    }
    stage16(row + 128, u, (size_t)g * DD + q * 16, f32);
  }
  __syncthreads();

  const f32x4 vzero = {0.f, 0.f, 0.f, 0.f};
  const int colbase = wave * 32;
  const int n0      = wave * 16;

  // ---- node MLP layer 1: K=192 ----
  f32x4 acc[4][2];
  #pragma unroll
  for (int rt = 0; rt < 4; ++rt){ acc[rt][0] = vzero; acc[rt][1] = vzero; }
  for (int kk = 0; kk < 6; ++kk){
    bf16x8 af[4], bw[2];
    #pragma unroll
    for (int rt = 0; rt < 4; ++rt)
      af[rt] = ldfrag(&sA[(rt * 16 + l15) * NAS + kk * 32 + quad * 8]);
    #pragma unroll
    for (int ct = 0; ct < 2; ++ct)
      bw[ct] = ldfrag(&WpN1[((kk * HH + colbase + ct * 16 + l15) << 5) + quad * 8]);
    #pragma unroll
    for (int rt = 0; rt < 4; ++rt)
      #pragma unroll
      for (int ct = 0; ct < 2; ++ct)
        acc[rt][ct] = __builtin_amdgcn_mfma_f32_16x16x32_bf16(af[rt], bw[ct], acc[rt][ct], 0, 0, 0);
  }
  #pragma unroll
  for (int ct = 0; ct < 2; ++ct){
    const int col = colbase + ct * 16 + l15;
    const float bias = ldb(bn1, col, f32);
    #pragma unroll
    for (int rt = 0; rt < 4; ++rt)
      #pragma unroll
      for (int r = 0; r < 4; ++r){
        float h = fmaxf(acc[rt][ct][r] + bias, 0.f);
        sH[(rt * 16 + quad * 4 + r) * HS + col] = f2bf(h);
      }
  }
  __syncthreads();

  // ---- node MLP layer 2 -> x_new ----
  f32x4 acc2[4];
  #pragma unroll
  for (int rt = 0; rt < 4; ++rt) acc2[rt] = vzero;
  for (int kk = 0; kk < 4; ++kk){
    bf16x8 af[4];
    #pragma unroll
    for (int rt = 0; rt < 4; ++rt)
      af[rt] = ldfrag(&sH[(rt * 16 + l15) * HS + kk * 32 + quad * 8]);
    bf16x8 bw = ldfrag(&WpN2[((kk * 64 + n0 + l15) << 5) + quad * 8]);
    #pragma unroll
    for (int rt = 0; rt < 4; ++rt)
      acc2[rt] = __builtin_amdgcn_mfma_f32_16x16x32_bf16(af[rt], bw, acc2[rt], 0, 0, 0);
  }
  {
    const int col = n0 + l15;
    const float bias = ldb(bn2, col, f32);
    #pragma unroll
    for (int rt = 0; rt < 4; ++rt)
      #pragma unroll
      for (int r = 0; r < 4; ++r){
        const int row = rt * 16 + quad * 4 + r;
        const int n = base + row;
        if (n < NN){
          float v = acc2[rt][r] + bias;
          store1(d_out, (size_t)n * DD + col, v, f32);
          atomicAdd(&sNagg[sGn[row] * DD + col], v);
        }
      }
  }
  __syncthreads();
  for (int i = tid; i < NG * DD; i += 256)
    atomicAdd(&node_agg[i], sNagg[i]);
}

__global__ __launch_bounds__(256) void global_kernel(
  const void* __restrict__ u, const float* __restrict__ node_agg, const float* __restrict__ edge_agg,
  const void* __restrict__ Wg1, const void* __restrict__ bg1,
  const void* __restrict__ Wg2, const void* __restrict__ bg2,
  void* __restrict__ d_out, const int* __restrict__ flag)
{
  __shared__ float sIn[NG * 192];
  __shared__ float sHg[NG * HH];
  const bool f32 = (*flag != 0);
  const size_t OUT_U = (size_t)NN * DD + (size_t)NE * DD;
  const int tid = threadIdx.x;
  for (int i = tid; i < NG * 192; i += 256){
    int g = i / 192, c = i - g * 192;
    float v;
    if      (c <  64) v = ldb(u, g * 64 + c, f32);
    else if (c < 128) v = node_agg[g * 64 + (c - 64)];
    else              v = edge_agg[g * 64 + (c - 128)];
    sIn[i] = v;
  }
  __syncthreads();
  for (int i = tid; i < NG * HH; i += 256){
    int g = i >> 7, j = i & 127;
    float s = ldb(bg1, j, f32);
    for (int k = 0; k < 192; ++k)
      s += sIn[g * 192 + k] * ldb(Wg1, k * 128 + j, f32);
    sHg[i] = fmaxf(s, 0.f);
  }
  __syncthreads();
  for (int i = tid; i < NG * DD; i += 256){
    int g = i >> 6, j = i & 63;
    float s = ldb(bg2, j, f32);
    for (int k = 0; k < 128; ++k)
      s += sHg[g * 128 + k] * ldb(Wg2, k * 64 + j, f32);
    store1(d_out, OUT_U + i, s, f32);
  }
}

extern "C" void kernel_launch(void* const* d_in, const int* in_sizes, int n_in,
                              void* d_out, int out_size, void* d_ws, size_t ws_size,
                              hipStream_t stream)
{
  const void* x     = d_in[0];
  const int*  ei    = (const int*)d_in[1];
  const void* e     = d_in[2];
  const void* u     = d_in[3];
  const int*  batch = (const int*)d_in[4];
  const void* We1 = d_in[5];
  const void* be1 = d_in[6];
  const void* We2 = d_in[7];
  const void* be2 = d_in[8];
  const void* Wa1 = d_in[9];
  const void* ba1 = d_in[10];
  const void* Wa2 = d_in[11];
  const void* ba2 = d_in[12];
  const void* Wn1 = d_in[13];
  const void* bn1 = d_in[14];
  const void* Wn2 = d_in[15];
  const void* bn2 = d_in[16];
  const void* Wg1 = d_in[17];
  const void* bg1 = d_in[18];
  const void* Wg2 = d_in[19];
  const void* bg2 = d_in[20];

  // workspace layout: [flag(16B)] [agg NN*DD f32] [edge_agg] [node_agg] [packed weights]
  int*   flag     = (int*)d_ws;
  float* agg      = (float*)((char*)d_ws + 16);
  float* edge_agg = agg + (size_t)NN * DD;
  float* node_agg = edge_agg + NG * DD;
  u16t*  wp    = (u16t*)(node_agg + NG * DD);
  u16t*  Wp_e1 = wp; wp += 256 * 128;
  u16t*  Wp_e2 = wp; wp += 128 * 64;
  u16t*  Wp_a1 = wp; wp += 256 * 128;
  u16t*  Wp_a2 = wp; wp += 128 * 64;
  u16t*  Wp_n1 = wp; wp += 192 * 128;
  u16t*  Wp_n2 = wp; wp += 128 * 64;

  detect_kernel<<<1, 64, 0, stream>>>(x, flag);
  hipMemsetAsync(agg, 0, ((size_t)NN * DD + 2 * NG * DD) * sizeof(float), stream);

  repack_kernel<<<(256 * 128 + 255) / 256, 256, 0, stream>>>(We1, Wp_e1, 256, 128, flag);
  repack_kernel<<<(128 * 64  + 255) / 256, 256, 0, stream>>>(We2, Wp_e2, 128, 64, flag);
  repack_kernel<<<(256 * 128 + 255) / 256, 256, 0, stream>>>(Wa1, Wp_a1, 256, 128, flag);
  repack_kernel<<<(128 * 64  + 255) / 256, 256, 0, stream>>>(Wa2, Wp_a2, 128, 64, flag);
  repack_kernel<<<(192 * 128 + 255) / 256, 256, 0, stream>>>(Wn1, Wp_n1, 192, 128, flag);
  repack_kernel<<<(128 * 64  + 255) / 256, 256, 0, stream>>>(Wn2, Wp_n2, 128, 64, flag);

  edge_kernel<<<1024, 256, 0, stream>>>(x, ei, e, u, batch,
      Wp_e1, be1, Wp_e2, be2, Wp_a1, ba1, Wp_a2, ba2,
      d_out, agg, edge_agg, flag, NE / 64);

  node_kernel<<<(NN + 63) / 64, 256, 0, stream>>>(x, agg, u, batch,
      Wp_n1, bn1, Wp_n2, bn2, d_out, node_agg, flag);

  global_kernel<<<1, 256, 0, stream>>>(u, node_agg, edge_agg,
      Wg1, bg1, Wg2, bg2, d_out, flag);
}